// Round 1
// baseline (86.561 us; speedup 1.0000x reference)
//
#include <hip/hip_runtime.h>

// DarkNet53 grid decode:
//   in : [B=32, A*ATTR=255, 76, 76] f32   (c = a*85 + attr)
//   out: [B, A*76*76, 85] f32, row (b, a, j, i) -> [obj, x, y, w, h, conf...]
// obj = sigmoid(f0); x=(sigmoid(f1)+i)*8; y=(sigmoid(f2)+j)*8;
// w = aw*exp(f3)*8; h = ah*exp(f4)*8; conf = raw.

#define A_    3
#define ATTR_ 85
#define GW_   76
#define SP_   (76 * 76)   // 5776 spatial positions per plane
#define TS    128         // spatial tile per block
#define NT    256         // threads per block

__global__ __launch_bounds__(NT) void darknet_decode_kernel(
    const float* __restrict__ in,
    const float* __restrict__ anchors,
    float* __restrict__ out) {

    const int tile  = blockIdx.x;            // 0..45
    const int plane = blockIdx.y;            // b*A + a
    const int a     = plane % A_;

    const int s0   = tile * TS;
    const int send = (s0 + TS < SP_) ? (s0 + TS) : SP_;
    const int ns   = send - s0;              // 128 or 16 (tail)

    __shared__ float lds[TS * ATTR_];        // [spatial][attr], stride 85 (odd -> banks spread)

    const float aw = anchors[2 * a]     * 8.0f;
    const float ah = anchors[2 * a + 1] * 8.0f;

    const float* __restrict__ inp = in + (size_t)plane * (ATTR_ * SP_);

    const int tx4   = threadIdx.x & 31;      // 32 spatial quads -> 128 positions
    const int ty    = threadIdx.x >> 5;      // 8 attr groups
    const int sbase = 4 * tx4;

    if (sbase < ns) {
        // per-thread grid coords for its 4 spatial positions (only needed for attr 1/2)
        for (int attr = ty; attr < ATTR_; attr += 8) {
            const float4 v4 = *reinterpret_cast<const float4*>(inp + (size_t)attr * SP_ + s0 + sbase);
            float vv[4] = {v4.x, v4.y, v4.z, v4.w};
            #pragma unroll
            for (int k = 0; k < 4; ++k) {
                const int s = s0 + sbase + k;
                const float v = vv[k];
                float r;
                if (attr >= 5) {
                    r = v;                                   // class confidences: raw
                } else if (attr == 0) {
                    r = 1.0f / (1.0f + __expf(-v));          // objness
                } else if (attr == 1) {
                    const int i = s % GW_;
                    r = (1.0f / (1.0f + __expf(-v)) + (float)i) * 8.0f;
                } else if (attr == 2) {
                    const int j = s / GW_;
                    r = (1.0f / (1.0f + __expf(-v)) + (float)j) * 8.0f;
                } else if (attr == 3) {
                    r = aw * __expf(v);
                } else {                                     // attr == 4
                    r = ah * __expf(v);
                }
                lds[(sbase + k) * ATTR_ + attr] = r;
            }
        }
    }
    __syncthreads();

    // Output chunk for this tile is contiguous: ns*85 floats, 16B-aligned.
    float* __restrict__ outp = out + (size_t)plane * ((size_t)SP_ * ATTR_) + (size_t)s0 * ATTR_;
    const int nf4 = (ns * ATTR_) >> 2;                       // 2720 or 340
    const float4* __restrict__ lds4 = reinterpret_cast<const float4*>(lds);
    float4* __restrict__ out4 = reinterpret_cast<float4*>(outp);
    for (int idx = threadIdx.x; idx < nf4; idx += NT) {
        out4[idx] = lds4[idx];
    }
}

extern "C" void kernel_launch(void* const* d_in, const int* in_sizes, int n_in,
                              void* d_out, int out_size, void* d_ws, size_t ws_size,
                              hipStream_t stream) {
    const float* features = (const float*)d_in[0];
    const float* anchors  = (const float*)d_in[1];
    float* out = (float*)d_out;

    const int tiles_per_plane = (SP_ + TS - 1) / TS;   // 46
    const int planes = 32 * A_;                        // 96
    dim3 grid(tiles_per_plane, planes);
    darknet_decode_kernel<<<grid, NT, 0, stream>>>(features, anchors, out);
}

// Round 2
// 75.270 us; speedup vs baseline: 1.1500x; 1.1500x over previous
//
#include <hip/hip_runtime.h>

// DarkNet53 grid decode:
//   in : [B=32, A*ATTR=255, 76, 76] f32   (c = a*85 + attr)
//   out: [B, A*76*76, 85] f32, row (b, a, j, i) -> [obj, x, y, w, h, conf...]
// obj = sigmoid(f0); x=(sigmoid(f1)+i)*8; y=(sigmoid(f2)+j)*8;
// w = aw*exp(f3)*8; h = ah*exp(f4)*8; conf = raw.

#define A_    3
#define ATTR_ 85
#define GW_   76
#define SP_   (76 * 76)   // 5776 spatial positions per plane
#define TS    64          // spatial tile per block (LDS 21.76 KB -> 7 blocks/CU)
#define NT    256         // threads per block

__global__ __launch_bounds__(NT) void darknet_decode_kernel(
    const float* __restrict__ in,
    const float* __restrict__ anchors,
    float* __restrict__ out) {

    const int tile  = blockIdx.x;            // 0..90
    const int plane = blockIdx.y;            // b*A + a
    const int a     = plane % A_;

    const int s0   = tile * TS;
    const int send = (s0 + TS < SP_) ? (s0 + TS) : SP_;
    const int ns   = send - s0;              // 64 or 16 (tail)

    __shared__ float lds[TS * ATTR_];        // [spatial][attr], stride 85 (odd -> banks spread)

    const float aw = anchors[2 * a]     * 8.0f;
    const float ah = anchors[2 * a + 1] * 8.0f;

    const float* __restrict__ inp = in + (size_t)plane * (ATTR_ * SP_);

    const int tx4   = threadIdx.x & 15;      // 16 spatial quads -> 64 positions
    const int ty    = threadIdx.x >> 4;      // 16 attr groups
    const int sbase = 4 * tx4;

    if (sbase < ns) {
        for (int attr = ty; attr < ATTR_; attr += 16) {
            const float4 v4 = *reinterpret_cast<const float4*>(inp + (size_t)attr * SP_ + s0 + sbase);
            float vv[4] = {v4.x, v4.y, v4.z, v4.w};
            #pragma unroll
            for (int k = 0; k < 4; ++k) {
                const int s = s0 + sbase + k;
                const float v = vv[k];
                float r;
                if (attr >= 5) {
                    r = v;                                   // class confidences: raw
                } else if (attr == 0) {
                    r = 1.0f / (1.0f + __expf(-v));          // objness
                } else if (attr == 1) {
                    const int i = s % GW_;
                    r = (1.0f / (1.0f + __expf(-v)) + (float)i) * 8.0f;
                } else if (attr == 2) {
                    const int j = s / GW_;
                    r = (1.0f / (1.0f + __expf(-v)) + (float)j) * 8.0f;
                } else if (attr == 3) {
                    r = aw * __expf(v);
                } else {                                     // attr == 4
                    r = ah * __expf(v);
                }
                lds[(sbase + k) * ATTR_ + attr] = r;
            }
        }
    }
    __syncthreads();

    // Output chunk for this tile is contiguous: ns*85 floats, 16B-aligned.
    float* __restrict__ outp = out + (size_t)plane * ((size_t)SP_ * ATTR_) + (size_t)s0 * ATTR_;
    const int nf4 = (ns * ATTR_) >> 2;                       // 1360 or 340
    const float4* __restrict__ lds4 = reinterpret_cast<const float4*>(lds);
    float4* __restrict__ out4 = reinterpret_cast<float4*>(outp);
    for (int idx = threadIdx.x; idx < nf4; idx += NT) {
        out4[idx] = lds4[idx];
    }
}

extern "C" void kernel_launch(void* const* d_in, const int* in_sizes, int n_in,
                              void* d_out, int out_size, void* d_ws, size_t ws_size,
                              hipStream_t stream) {
    const float* features = (const float*)d_in[0];
    const float* anchors  = (const float*)d_in[1];
    float* out = (float*)d_out;

    const int tiles_per_plane = (SP_ + TS - 1) / TS;   // 91
    const int planes = 32 * A_;                        // 96
    dim3 grid(tiles_per_plane, planes);
    darknet_decode_kernel<<<grid, NT, 0, stream>>>(features, anchors, out);
}

// Round 4
// 66.115 us; speedup vs baseline: 1.3093x; 1.1385x over previous
//
#include <hip/hip_runtime.h>

// DarkNet53 grid decode:
//   in : [B=32, A*ATTR=255, 76, 76] f32   (c = a*85 + attr)
//   out: [B, A*76*76, 85] f32, row (b, a, j, i) -> [obj, x, y, w, h, conf...]
// obj = sigmoid(f0); x=(sigmoid(f1)+i)*8; y=(sigmoid(f2)+j)*8;
// w = aw*exp(f3)*8; h = ah*exp(f4)*8; conf = raw.

#define A_    3
#define ATTR_ 85
#define GW_   76
#define SP_   (76 * 76)   // 5776 spatial positions per plane
#define TS    64          // spatial tile per block (LDS 21.76 KB -> 7 blocks/CU)
#define NT    256         // threads per block

typedef float f32x4 __attribute__((ext_vector_type(4)));  // native vector: OK for nontemporal builtins

__global__ __launch_bounds__(NT) void darknet_decode_kernel(
    const float* __restrict__ in,
    const float* __restrict__ anchors,
    float* __restrict__ out) {

    const int tile  = blockIdx.x;            // 0..90
    const int plane = blockIdx.y;            // b*A + a
    const int a     = plane % A_;

    const int s0 = tile * TS;
    const int ns = (SP_ - s0 < TS) ? (SP_ - s0) : TS;   // 64 or 16 (tail)

    __shared__ float lds[TS * ATTR_];        // [spatial][attr]

    const float aw = anchors[2 * a]     * 8.0f;
    const float ah = anchors[2 * a + 1] * 8.0f;

    const float* __restrict__ inp = in + (size_t)plane * (ATTR_ * SP_) + s0;

    const int tx4   = threadIdx.x & 15;      // 16 spatial quads -> 64 positions
    const int ty    = threadIdx.x >> 4;      // 16 attr groups
    const int sbase = 4 * tx4;

    if (sbase < ns) {
        // ---- batch all independent loads first (5 or 6 outstanding) ----
        f32x4 v[6];
        #pragma unroll
        for (int it = 0; it < 5; ++it) {
            v[it] = *reinterpret_cast<const f32x4*>(inp + (size_t)(ty + 16 * it) * SP_ + sbase);
        }
        const bool six = (ty < 5);           // attrs 80..84
        if (six) {
            v[5] = *reinterpret_cast<const f32x4*>(inp + (size_t)(80 + ty) * SP_ + sbase);
        }

        // ---- transform specials (attr = ty at it==0, only ty<5 special) ----
        if (ty < 5) {
            #pragma unroll
            for (int k = 0; k < 4; ++k) {
                const int s = s0 + sbase + k;
                const float x = v[0][k];
                float r;
                if (ty == 0)      r = 1.0f / (1.0f + __expf(-x));
                else if (ty == 1) r = (1.0f / (1.0f + __expf(-x)) + (float)(s % GW_)) * 8.0f;
                else if (ty == 2) r = (1.0f / (1.0f + __expf(-x)) + (float)(s / GW_)) * 8.0f;
                else if (ty == 3) r = aw * __expf(x);
                else              r = ah * __expf(x);
                v[0][k] = r;
            }
        }

        // ---- scatter to LDS [s][attr] (writes don't stall the wave) ----
        #pragma unroll
        for (int it = 0; it < 5; ++it) {
            const int attr = ty + 16 * it;
            #pragma unroll
            for (int k = 0; k < 4; ++k)
                lds[(sbase + k) * ATTR_ + attr] = v[it][k];
        }
        if (six) {
            const int attr = 80 + ty;
            #pragma unroll
            for (int k = 0; k < 4; ++k)
                lds[(sbase + k) * ATTR_ + attr] = v[5][k];
        }
    }
    __syncthreads();

    // ---- linear LDS -> global, batched reads then nt stores ----
    float* __restrict__ outp = out + (size_t)plane * ((size_t)SP_ * ATTR_) + (size_t)s0 * ATTR_;
    const int nf4 = (ns * ATTR_) >> 2;                        // 1360 or 340
    const f32x4* __restrict__ lds4 = reinterpret_cast<const f32x4*>(lds);
    f32x4* __restrict__ out4 = reinterpret_cast<f32x4*>(outp);

    f32x4 w[6];
    #pragma unroll
    for (int it = 0; it < 6; ++it) {
        const int idx = (int)threadIdx.x + NT * it;
        if (idx < nf4) w[it] = lds4[idx];
    }
    #pragma unroll
    for (int it = 0; it < 6; ++it) {
        const int idx = (int)threadIdx.x + NT * it;
        if (idx < nf4) __builtin_nontemporal_store(w[it], &out4[idx]);
    }
}

extern "C" void kernel_launch(void* const* d_in, const int* in_sizes, int n_in,
                              void* d_out, int out_size, void* d_ws, size_t ws_size,
                              hipStream_t stream) {
    const float* features = (const float*)d_in[0];
    const float* anchors  = (const float*)d_in[1];
    float* out = (float*)d_out;

    const int tiles_per_plane = (SP_ + TS - 1) / TS;   // 91
    const int planes = 32 * A_;                        // 96
    dim3 grid(tiles_per_plane, planes);
    darknet_decode_kernel<<<grid, NT, 0, stream>>>(features, anchors, out);
}

// Round 5
// 65.765 us; speedup vs baseline: 1.3162x; 1.0053x over previous
//
#include <hip/hip_runtime.h>

// DarkNet53 grid decode:
//   in : [B=32, A*ATTR=255, 76, 76] f32   (c = a*85 + attr)
//   out: [B, A*76*76, 85] f32, row (b, a, j, i) -> [obj, x, y, w, h, conf...]
// obj = sigmoid(f0); x=(sigmoid(f1)+i)*8; y=(sigmoid(f2)+j)*8;
// w = aw*exp(f3)*8; h = ah*exp(f4)*8; conf = raw.

#define A_    3
#define ATTR_ 85
#define GW_   76
#define SP_   (76 * 76)   // 5776 spatial positions per plane
#define TS    96          // spatial tile per block: LDS 32640B -> 32768 alloc -> 5 blocks/CU = 30 waves
#define NT    384         // threads: 16 attr-groups x 24 spatial-quads

typedef float f32x4 __attribute__((ext_vector_type(4)));

__global__ __launch_bounds__(NT) void darknet_decode_kernel(
    const float* __restrict__ in,
    const float* __restrict__ anchors,
    float* __restrict__ out) {

    const int tile  = blockIdx.x;            // 0..60
    const int plane = blockIdx.y;            // b*A + a
    const int a     = plane % A_;

    const int s0 = tile * TS;
    const int ns = (SP_ - s0 < TS) ? (SP_ - s0) : TS;   // 96 or 16 (tail)

    __shared__ float lds[TS * ATTR_];        // [spatial][attr]

    const float aw = anchors[2 * a]     * 8.0f;
    const float ah = anchors[2 * a + 1] * 8.0f;

    const float* __restrict__ inp = in + (size_t)plane * (ATTR_ * SP_) + s0;

    const int q     = threadIdx.x % 24;      // 24 spatial quads -> 96 positions
    const int g     = threadIdx.x / 24;      // 16 attr groups
    const int sbase = 4 * q;

    if (sbase < ns) {
        // ---- batch all independent loads first (5 or 6 outstanding) ----
        f32x4 v[6];
        #pragma unroll
        for (int it = 0; it < 5; ++it) {
            v[it] = *reinterpret_cast<const f32x4*>(inp + (size_t)(g + 16 * it) * SP_ + sbase);
        }
        const bool six = (g < 5);            // attrs 80..84
        if (six) {
            v[5] = *reinterpret_cast<const f32x4*>(inp + (size_t)(80 + g) * SP_ + sbase);
        }

        // ---- transform specials (attr = g at it==0, only g<5 special) ----
        if (g < 5) {
            #pragma unroll
            for (int k = 0; k < 4; ++k) {
                const int s = s0 + sbase + k;
                const float x = v[0][k];
                float r;
                if (g == 0)      r = 1.0f / (1.0f + __expf(-x));
                else if (g == 1) r = (1.0f / (1.0f + __expf(-x)) + (float)(s % GW_)) * 8.0f;
                else if (g == 2) r = (1.0f / (1.0f + __expf(-x)) + (float)(s / GW_)) * 8.0f;
                else if (g == 3) r = aw * __expf(x);
                else             r = ah * __expf(x);
                v[0][k] = r;
            }
        }

        // ---- scatter to LDS [s][attr] ----
        #pragma unroll
        for (int it = 0; it < 5; ++it) {
            const int attr = g + 16 * it;
            #pragma unroll
            for (int k = 0; k < 4; ++k)
                lds[(sbase + k) * ATTR_ + attr] = v[it][k];
        }
        if (six) {
            const int attr = 80 + g;
            #pragma unroll
            for (int k = 0; k < 4; ++k)
                lds[(sbase + k) * ATTR_ + attr] = v[5][k];
        }
    }
    __syncthreads();

    // ---- linear LDS -> global, batched reads then nt stores ----
    float* __restrict__ outp = out + (size_t)plane * ((size_t)SP_ * ATTR_) + (size_t)s0 * ATTR_;
    const int nf4 = (ns * ATTR_) >> 2;                        // 2040 or 340
    const f32x4* __restrict__ lds4 = reinterpret_cast<const f32x4*>(lds);
    f32x4* __restrict__ out4 = reinterpret_cast<f32x4*>(outp);

    f32x4 w[6];
    #pragma unroll
    for (int it = 0; it < 6; ++it) {
        const int idx = (int)threadIdx.x + NT * it;
        if (idx < nf4) w[it] = lds4[idx];
    }
    #pragma unroll
    for (int it = 0; it < 6; ++it) {
        const int idx = (int)threadIdx.x + NT * it;
        if (idx < nf4) __builtin_nontemporal_store(w[it], &out4[idx]);
    }
}

extern "C" void kernel_launch(void* const* d_in, const int* in_sizes, int n_in,
                              void* d_out, int out_size, void* d_ws, size_t ws_size,
                              hipStream_t stream) {
    const float* features = (const float*)d_in[0];
    const float* anchors  = (const float*)d_in[1];
    float* out = (float*)d_out;

    const int tiles_per_plane = (SP_ + TS - 1) / TS;   // 61
    const int planes = 32 * A_;                        // 96
    dim3 grid(tiles_per_plane, planes);
    darknet_decode_kernel<<<grid, NT, 0, stream>>>(features, anchors, out);
}

// Round 6
// 65.592 us; speedup vs baseline: 1.3197x; 1.0026x over previous
//
#include <hip/hip_runtime.h>

// DarkNet53 grid decode, barrier-free wave-local transpose.
//   in : [B=32, A*ATTR=255, 76, 76] f32   (c = a*85 + attr)
//   out: [B, A*76*76, 85] f32
// Each wave owns a 16-spatial-position chunk: loads 85 attr rows (64B
// segments), transforms attrs 0-4, transposes via its private 5440B LDS
// region (within-wave dep -> lgkmcnt only, NO __syncthreads), then writes
// one contiguous 5440B output chunk with nt float4 stores.

#define A_     3
#define ATTR_  85
#define GW_    76
#define SP_    (76 * 76)    // 5776 = 361 chunks of 16  (exact, no tail)
#define NCHUNK 361
#define WAVES  4            // per block
#define CPW    2            // chunks per wave (software pipeline depth)
#define NT     256

typedef float f32x4 __attribute__((ext_vector_type(4)));

__global__ __launch_bounds__(NT) void darknet_decode_kernel(
    const float* __restrict__ in,
    const float* __restrict__ anchors,
    float* __restrict__ out) {

    const int plane = blockIdx.y;            // b*A + a
    const int a     = plane % A_;
    const int wv    = threadIdx.x >> 6;      // wave id 0..3
    const int l     = threadIdx.x & 63;      // lane
    const int al    = l >> 2;                // attr sub-index 0..15
    const int pq    = l & 3;                 // position quad 0..3

    __shared__ float lds[WAVES * 16 * ATTR_];     // 5440B per wave
    float* __restrict__ wl = lds + wv * (16 * ATTR_);

    const float aw = anchors[2 * a]     * 8.0f;
    const float ah = anchors[2 * a + 1] * 8.0f;

    const float* __restrict__ inp = in + (size_t)plane * ((size_t)ATTR_ * SP_);
    const int c0 = blockIdx.x * (WAVES * CPW) + wv * CPW;   // plane-local chunk

    // ---- issue ALL loads for both chunks up front (up to 12 in flight) ----
    f32x4 v[CPW][6];
    #pragma unroll
    for (int j = 0; j < CPW; ++j) {
        const int c = c0 + j;                // wave-uniform
        if (c < NCHUNK) {
            const float* p = inp + c * 16 + 4 * pq;
            #pragma unroll
            for (int it = 0; it < 5; ++it)
                v[j][it] = *reinterpret_cast<const f32x4*>(p + (size_t)(16 * it + al) * SP_);
            if (al < 5)
                v[j][5] = *reinterpret_cast<const f32x4*>(p + (size_t)(80 + al) * SP_);
        }
    }

    // ---- per chunk: transform -> LDS transpose -> linear nt store ----
    #pragma unroll
    for (int j = 0; j < CPW; ++j) {
        const int c = c0 + j;
        if (c < NCHUNK) {
            // transform specials (attrs 0..4 live in v[j][0] on lanes al<5)
            if (al < 5) {
                #pragma unroll
                for (int k = 0; k < 4; ++k) {
                    const int s = c * 16 + 4 * pq + k;
                    const float x = v[j][0][k];
                    float r;
                    if (al == 0)      r = 1.0f / (1.0f + __expf(-x));
                    else if (al == 1) r = (1.0f / (1.0f + __expf(-x)) + (float)(s % GW_)) * 8.0f;
                    else if (al == 2) r = (1.0f / (1.0f + __expf(-x)) + (float)(s / GW_)) * 8.0f;
                    else if (al == 3) r = aw * __expf(x);
                    else              r = ah * __expf(x);
                    v[j][0][k] = r;
                }
            }

            // scatter into wave-private LDS [pos][attr]
            #pragma unroll
            for (int it = 0; it < 5; ++it) {
                const int attr = 16 * it + al;
                #pragma unroll
                for (int k = 0; k < 4; ++k)
                    wl[(4 * pq + k) * ATTR_ + attr] = v[j][it][k];
            }
            if (al < 5) {
                const int attr = 80 + al;
                #pragma unroll
                for (int k = 0; k < 4; ++k)
                    wl[(4 * pq + k) * ATTR_ + attr] = v[j][5][k];
            }

            // linear LDS read (340 f32x4) + contiguous nt stores
            const f32x4* __restrict__ wl4 = reinterpret_cast<const f32x4*>(wl);
            f32x4* __restrict__ op4 = reinterpret_cast<f32x4*>(
                out + ((size_t)plane * SP_ + (size_t)c * 16) * ATTR_);
            f32x4 t[6];
            #pragma unroll
            for (int it = 0; it < 5; ++it) t[it] = wl4[l + 64 * it];
            if (l < 20) t[5] = wl4[l + 320];
            #pragma unroll
            for (int it = 0; it < 5; ++it)
                __builtin_nontemporal_store(t[it], &op4[l + 64 * it]);
            if (l < 20)
                __builtin_nontemporal_store(t[5], &op4[l + 320]);
        }
    }
}

extern "C" void kernel_launch(void* const* d_in, const int* in_sizes, int n_in,
                              void* d_out, int out_size, void* d_ws, size_t ws_size,
                              hipStream_t stream) {
    const float* features = (const float*)d_in[0];
    const float* anchors  = (const float*)d_in[1];
    float* out = (float*)d_out;

    const int chunks_per_block = WAVES * CPW;                     // 8
    const int bx = (NCHUNK + chunks_per_block - 1) / chunks_per_block;  // 46
    dim3 grid(bx, 32 * A_);
    darknet_decode_kernel<<<grid, NT, 0, stream>>>(features, anchors, out);
}